// Round 7
// baseline (633.919 us; speedup 1.0000x reference)
//
#include <hip/hip_runtime.h>
#include <hip/hip_bf16.h>

#define N_NODES 20000
#define N_EDGES 320000
#define TOT_E   (N_EDGES + N_NODES)   // 340000 with self loops
#define IN_CH   128
#define HEADS   8
#define CH      33
#define DD      264                   // HEADS*CH
#define OUTW    132
#define NEG     0.2f

#define LDB     272                   // bf16 payload row stride
#define LDA     288                   // hA bf16 row stride, K padded to 9*32
#define NT_HID  18                    // 17 payload tiles + 1 stats tile [was|wad]
#define NT_HEAD 9                     // head gemm tiles (132 -> 144)

typedef unsigned short ushort;
typedef short bf16x8 __attribute__((ext_vector_type(8)));
typedef float f32x4  __attribute__((ext_vector_type(4)));

__device__ inline void split2(float v, ushort& hi, ushort& lo) {
    __hip_bfloat16 h = __float2bfloat16(v);
    float r = v - __bfloat162float(h);
    __hip_bfloat16 l = __float2bfloat16(r);
    hi = *(ushort*)&h;
    lo = *(ushort*)&l;
}

__device__ inline float bf2f(ushort u) {
    union { unsigned int i; float f; } c;
    c.i = ((unsigned int)u) << 16;
    return c.f;
}

// ---------------- CSR build ----------------

__global__ void deg_k(const int* __restrict__ ei, int* __restrict__ deg) {
    int e = blockIdx.x * 256 + threadIdx.x;
    if (e >= TOT_E) return;
    int dst = (e < N_EDGES) ? ei[N_EDGES + e] : (e - N_EDGES);
    atomicAdd(&deg[dst], 1);
}

__global__ __launch_bounds__(1024) void scan_k(const int* __restrict__ deg,
                                               int* __restrict__ rowp) {
    __shared__ int part[1024];
    const int PER = 20;
    int t = threadIdx.x;
    int base = t * PER;
    int s = 0;
    for (int i = 0; i < PER; ++i) {
        int idx = base + i;
        if (idx < N_NODES) s += deg[idx];
    }
    part[t] = s;
    __syncthreads();
    for (int off = 1; off < 1024; off <<= 1) {
        int v = 0;
        if (t >= off) v = part[t - off];
        __syncthreads();
        part[t] += v;
        __syncthreads();
    }
    int run = part[t] - s;
    for (int i = 0; i < PER; ++i) {
        int idx = base + i;
        if (idx < N_NODES) { rowp[idx] = run; run += deg[idx]; }
    }
    if (t == 1023) rowp[N_NODES] = part[1023];
}

__global__ void fill_k(const int* __restrict__ ei, const int* __restrict__ rowp,
                       int* __restrict__ cur, int* __restrict__ csr) {
    int e = blockIdx.x * 256 + threadIdx.x;
    if (e >= TOT_E) return;
    int src, dst;
    if (e < N_EDGES) { src = ei[e]; dst = ei[N_EDGES + e]; }
    else             { src = dst = e - N_EDGES; }
    int p = atomicAdd(&cur[dst], 1);
    csr[rowp[dst] + p] = src;
}

// ---------------- input x -> bf16 (into hAhi, stride LDA) ----------------

__global__ void splitx_k(const float* __restrict__ x, ushort* __restrict__ ahi) {
    int idx = blockIdx.x * 256 + threadIdx.x;
    if (idx >= N_NODES * IN_CH) return;
    int n = idx >> 7, k = idx & 127;
    __hip_bfloat16 h = __float2bfloat16(x[idx]);
    ahi[(size_t)n * LDA + k] = *(ushort*)&h;
}

// ---------------- weight -> fragment-ordered hi/lo bf16 (+ optional stats tile) ------
// Wfrag[((p*NT + t)*64 + kq*16 + m)*8 + j] = V[p*32 + kq*8 + j][t*16 + m]
// where V = W for t < NT-1 (or all t when a_s==null); last tile (when a_s given):
// col m<8: was[k][m] = sum_c W[k][m*33+c]*a_s[m*33+c]; col m>=8: wad with a_d.

__global__ void convw_k(const float* __restrict__ W, const float* __restrict__ a_s,
                        const float* __restrict__ a_d, int K, int NC, int NT,
                        ushort* __restrict__ fhi, ushort* __restrict__ flo,
                        int total) {
    int gid = blockIdx.x * 256 + threadIdx.x;
    if (gid >= total) return;   // total = panels*NT*64
    int p = gid / (NT * 64);
    int rem = gid % (NT * 64);
    int t = rem >> 6, c = rem & 63;
    int kq = c >> 4, m = c & 15;
    int n = t * 16 + m;
    bool stats = (a_s != nullptr) && (t == NT - 1);
    ushort hi8[8], lo8[8];
#pragma unroll
    for (int j = 0; j < 8; ++j) {
        int k = p * 32 + kq * 8 + j;
        float v = 0.f;
        if (k < K) {
            if (stats) {
                const float* av = (m < 8) ? a_s : a_d;
                int h = (m < 8) ? m : m - 8;
                const float* wr = W + (size_t)k * NC + h * CH;
                float s = 0.f;
                for (int cc = 0; cc < CH; ++cc) s += wr[cc] * av[h * CH + cc];
                v = s;
            } else if (n < NC) {
                v = W[(size_t)k * NC + n];
            }
        }
        split2(v, hi8[j], lo8[j]);
    }
    size_t o = ((size_t)gid) * 8;
#pragma unroll
    for (int j = 0; j < 8; ++j) { fhi[o + j] = hi8[j]; flo[o + j] = lo8[j]; }
}

// ---------------- MFMA GEMM, M-tile 128, register-prefetched B ----------------
// Wave w owns m-tiles 2w, 2w+1. Per panel: stage A to LDS, prefetch ALL B frags of
// the 9-tile group into registers, then MFMA burst. Hidden mode (C==null): writes
// bf16 payload for tiles<17 and as_/ad_ for tile 17. Head mode: fp32 C + bias.

__global__ __launch_bounds__(256) void gemm2_k(
    const ushort* __restrict__ Ahi, const ushort* __restrict__ Alo, int lda, int kpanels,
    const ushort* __restrict__ Bhi, const ushort* __restrict__ Blo, int NTtot,
    ushort* __restrict__ Cb16, float* __restrict__ as_, float* __restrict__ ad_,
    float* __restrict__ C, int ldc, int ncguard, const float* __restrict__ bias) {
    __shared__ ushort Al[2][8][512];   // [hi/lo][m-tile][chunk*8] = 16 KB
    int tid = threadIdx.x;
    int m0 = blockIdx.x * 128;
    int t0 = blockIdx.y * 9;
    int nt = NTtot - t0; if (nt > 9) nt = 9;
    bool use3 = (Alo != nullptr);

    f32x4 acc[2][9];
#pragma unroll
    for (int mt = 0; mt < 2; ++mt)
#pragma unroll
        for (int t = 0; t < 9; ++t) acc[mt][t] = (f32x4){0.f, 0.f, 0.f, 0.f};

    int w = tid >> 6, lane = tid & 63;

    for (int p = 0; p < kpanels; ++p) {
        int nA = use3 ? 1024 : 512;
        for (int id = tid; id < nA; id += 256) {
            int hl = id >> 9;
            int cid = id & 511;
            int mrow = cid >> 2, kq = cid & 3;
            int gm = m0 + mrow;
            uint4 v = {0, 0, 0, 0};
            if (gm < N_NODES) {
                const ushort* src = (hl ? Alo : Ahi) + (size_t)gm * lda + p * 32 + kq * 8;
                v = *(const uint4*)src;
            }
            *(uint4*)&Al[hl][mrow >> 4][(kq * 16 + (mrow & 15)) * 8] = v;
        }
        __syncthreads();

        bf16x8 a0 = *(const bf16x8*)&Al[0][2 * w][lane * 8];
        bf16x8 a1 = *(const bf16x8*)&Al[0][2 * w + 1][lane * 8];
        bf16x8 l0, l1;
        if (use3) {
            l0 = *(const bf16x8*)&Al[1][2 * w][lane * 8];
            l1 = *(const bf16x8*)&Al[1][2 * w + 1][lane * 8];
        }

        // prefetch all B fragments of this panel into registers
        bf16x8 bh[9], bl[9];
#pragma unroll
        for (int t = 0; t < 9; ++t) {
            if (t < nt) {
                size_t off = ((size_t)(p * NTtot + t0 + t) * 64 + lane) * 8;
                bh[t] = *(const bf16x8*)(Bhi + off);
                bl[t] = *(const bf16x8*)(Blo + off);
            }
        }
#pragma unroll
        for (int t = 0; t < 9; ++t) {
            if (t < nt) {
                acc[0][t] = __builtin_amdgcn_mfma_f32_16x16x32_bf16(a0, bh[t], acc[0][t], 0, 0, 0);
                acc[1][t] = __builtin_amdgcn_mfma_f32_16x16x32_bf16(a1, bh[t], acc[1][t], 0, 0, 0);
                acc[0][t] = __builtin_amdgcn_mfma_f32_16x16x32_bf16(a0, bl[t], acc[0][t], 0, 0, 0);
                acc[1][t] = __builtin_amdgcn_mfma_f32_16x16x32_bf16(a1, bl[t], acc[1][t], 0, 0, 0);
                if (use3) {
                    acc[0][t] = __builtin_amdgcn_mfma_f32_16x16x32_bf16(l0, bh[t], acc[0][t], 0, 0, 0);
                    acc[1][t] = __builtin_amdgcn_mfma_f32_16x16x32_bf16(l1, bh[t], acc[1][t], 0, 0, 0);
                }
            }
        }
        __syncthreads();
    }

    // store: C/D layout col = lane&15, row = (lane>>4)*4 + r
    int col = lane & 15;
#pragma unroll
    for (int mt = 0; mt < 2; ++mt) {
        int rbase = m0 + (2 * w + mt) * 16 + ((lane >> 4) << 2);
#pragma unroll
        for (int t = 0; t < 9; ++t) {
            if (t < nt) {
                int tg = t0 + t;
#pragma unroll
                for (int r = 0; r < 4; ++r) {
                    int gm = rbase + r;
                    if (gm >= N_NODES) continue;
                    float v = acc[mt][t][r];
                    if (C) {
                        int gn = tg * 16 + col;
                        if (gn < ncguard) C[(size_t)gm * ldc + gn] = v + bias[gn];
                    } else if (tg < 17) {
                        __hip_bfloat16 bv = __float2bfloat16(v);
                        Cb16[(size_t)gm * LDB + tg * 16 + col] = *(ushort*)&bv;
                    } else {
                        if (col < 8) as_[(size_t)gm * 8 + col] = v;
                        else         ad_[(size_t)gm * 8 + col - 8] = v;
                    }
                }
            }
        }
    }
}

// ---------------- fused softmax + gather-aggregate (unchanged from R6) ----------------

__global__ __launch_bounds__(256) void gat_k(
    const ushort* __restrict__ xb, const float* __restrict__ as_,
    const float* __restrict__ ad_, const int* __restrict__ rowp,
    const int* __restrict__ csr, const float* __restrict__ bias,
    ushort* __restrict__ outhi, ushort* __restrict__ outlo) {
    int wv = threadIdx.x >> 6, lane = threadIdx.x & 63;
    int node = blockIdx.x * 4 + wv;   // grid is exactly N/4
    int r0 = rowp[node], dg = rowp[node + 1] - r0;

    __shared__ float lex[4][64][8];
    __shared__ int   lsrc[4][64];
    __shared__ int   bdg[4];

    if (lane == 0) bdg[wv] = dg;
    __syncthreads();
    int bmax = max(max(bdg[0], bdg[1]), max(bdg[2], bdg[3]));
    int nchunks = (bmax + 63) >> 6;

    float ad[8];
#pragma unroll
    for (int h = 0; h < 8; ++h) ad[h] = ad_[node * 8 + h];

    float mx[8], iv[8], e8[8];
    int myS = node;
    bool fast = (dg <= 64);
    if (fast) {
#pragma unroll
        for (int h = 0; h < 8; ++h) e8[h] = -1e30f;
        if (lane < dg) {
            myS = csr[r0 + lane];
            const float* ap = as_ + (size_t)myS * 8;
#pragma unroll
            for (int h = 0; h < 8; ++h) {
                float e = ap[h] + ad[h];
                e8[h] = e > 0.f ? e : NEG * e;
            }
        }
#pragma unroll
        for (int h = 0; h < 8; ++h) {
            float m = e8[h];
            for (int off = 32; off; off >>= 1) m = fmaxf(m, __shfl_xor(m, off, 64));
            mx[h] = m;
        }
#pragma unroll
        for (int h = 0; h < 8; ++h) {
            float ex = (lane < dg) ? __expf(e8[h] - mx[h]) : 0.f;
            e8[h] = ex;
            float s = ex;
            for (int off = 32; off; off >>= 1) s += __shfl_xor(s, off, 64);
            iv[h] = 1.0f / (s + 1e-16f);
        }
    } else {
#pragma unroll
        for (int h = 0; h < 8; ++h) mx[h] = -1e30f;
        for (int j = lane; j < dg; j += 64) {
            int s = csr[r0 + j];
            const float* ap = as_ + (size_t)s * 8;
#pragma unroll
            for (int h = 0; h < 8; ++h) {
                float e = ap[h] + ad[h];
                e = e > 0.f ? e : NEG * e;
                mx[h] = fmaxf(mx[h], e);
            }
        }
#pragma unroll
        for (int h = 0; h < 8; ++h)
            for (int off = 32; off; off >>= 1)
                mx[h] = fmaxf(mx[h], __shfl_xor(mx[h], off, 64));
        float sm[8] = {0.f, 0.f, 0.f, 0.f, 0.f, 0.f, 0.f, 0.f};
        for (int j = lane; j < dg; j += 64) {
            int s = csr[r0 + j];
            const float* ap = as_ + (size_t)s * 8;
#pragma unroll
            for (int h = 0; h < 8; ++h) {
                float e = ap[h] + ad[h];
                e = e > 0.f ? e : NEG * e;
                sm[h] += __expf(e - mx[h]);
            }
        }
#pragma unroll
        for (int h = 0; h < 8; ++h) {
            for (int off = 32; off; off >>= 1) sm[h] += __shfl_xor(sm[h], off, 64);
            iv[h] = 1.0f / (sm[h] + 1e-16f);
        }
    }

    int h0[4], h1[4];
#pragma unroll
    for (int j = 0; j < 4; ++j) {
        h0[j] = (4 * lane + j) / 33;
        h1[j] = (4 * (lane + 64) + j) / 33;   // lanes 0,1 only (always head 7)
    }
    float4 a0 = {0.f, 0.f, 0.f, 0.f}, a1 = {0.f, 0.f, 0.f, 0.f};

    for (int c = 0; c < nchunks; ++c) {
        int base = c << 6, j = base + lane;
        __syncthreads();
        int s = node;
        float al[8];
#pragma unroll
        for (int h = 0; h < 8; ++h) al[h] = 0.f;
        if (j < dg) {
            if (fast) {
                s = myS;
#pragma unroll
                for (int h = 0; h < 8; ++h) al[h] = e8[h] * iv[h];
            } else {
                s = csr[r0 + j];
                const float* ap = as_ + (size_t)s * 8;
#pragma unroll
                for (int h = 0; h < 8; ++h) {
                    float e = ap[h] + ad[h];
                    e = e > 0.f ? e : NEG * e;
                    al[h] = __expf(e - mx[h]) * iv[h];
                }
            }
        }
        lsrc[wv][lane] = s;
#pragma unroll
        for (int h = 0; h < 8; ++h) lex[wv][lane][h] = al[h];
        __syncthreads();

        int rem = dg - base;
        int cnt = rem > 64 ? 64 : (rem < 0 ? 0 : rem);
        int cnt4 = (cnt + 3) & ~3;
        for (int jj = 0; jj < cnt4; jj += 4) {
            int s0 = lsrc[wv][jj + 0], s1 = lsrc[wv][jj + 1];
            int s2 = lsrc[wv][jj + 2], s3 = lsrc[wv][jj + 3];
            const ushort4* p0 = (const ushort4*)(xb + (size_t)s0 * LDB);
            const ushort4* p1 = (const ushort4*)(xb + (size_t)s1 * LDB);
            const ushort4* p2 = (const ushort4*)(xb + (size_t)s2 * LDB);
            const ushort4* p3 = (const ushort4*)(xb + (size_t)s3 * LDB);
            ushort4 v0 = p0[lane], v1 = p1[lane], v2 = p2[lane], v3 = p3[lane];
            ushort4 w0, w1, w2, w3;
            if (lane < 2) { w0 = p0[64 + lane]; w1 = p1[64 + lane]; w2 = p2[64 + lane]; w3 = p3[64 + lane]; }
            const float* x0 = lex[wv][jj + 0];
            const float* x1 = lex[wv][jj + 1];
            const float* x2 = lex[wv][jj + 2];
            const float* x3 = lex[wv][jj + 3];
            a0.x += x0[h0[0]] * bf2f(v0.x) + x1[h0[0]] * bf2f(v1.x)
                  + x2[h0[0]] * bf2f(v2.x) + x3[h0[0]] * bf2f(v3.x);
            a0.y += x0[h0[1]] * bf2f(v0.y) + x1[h0[1]] * bf2f(v1.y)
                  + x2[h0[1]] * bf2f(v2.y) + x3[h0[1]] * bf2f(v3.y);
            a0.z += x0[h0[2]] * bf2f(v0.z) + x1[h0[2]] * bf2f(v1.z)
                  + x2[h0[2]] * bf2f(v2.z) + x3[h0[2]] * bf2f(v3.z);
            a0.w += x0[h0[3]] * bf2f(v0.w) + x1[h0[3]] * bf2f(v1.w)
                  + x2[h0[3]] * bf2f(v2.w) + x3[h0[3]] * bf2f(v3.w);
            if (lane < 2) {
                a1.x += x0[h1[0]] * bf2f(w0.x) + x1[h1[0]] * bf2f(w1.x)
                      + x2[h1[0]] * bf2f(w2.x) + x3[h1[0]] * bf2f(w3.x);
                a1.y += x0[h1[1]] * bf2f(w0.y) + x1[h1[1]] * bf2f(w1.y)
                      + x2[h1[1]] * bf2f(w2.y) + x3[h1[1]] * bf2f(w3.y);
                a1.z += x0[h1[2]] * bf2f(w0.z) + x1[h1[2]] * bf2f(w1.z)
                      + x2[h1[2]] * bf2f(w2.z) + x3[h1[2]] * bf2f(w3.z);
                a1.w += x0[h1[3]] * bf2f(w0.w) + x1[h1[3]] * bf2f(w1.w)
                      + x2[h1[3]] * bf2f(w2.w) + x3[h1[3]] * bf2f(w3.w);
            }
        }
    }

    // epilogue: bias + elu, bf16 (hi) out; lo only when requested (head-gemm input)
#pragma unroll
    for (int k = 0; k < 2; ++k) {
        int i4 = lane + 64 * k;
        if (i4 < 66) {
            float4 a = (k == 0) ? a0 : a1;
            float vals[4] = {a.x, a.y, a.z, a.w};
            ushort hi4[4], lo4[4];
#pragma unroll
            for (int j = 0; j < 4; ++j) {
                float v = vals[j] + bias[i4 * 4 + j];
                v = v > 0.f ? v : (__expf(v) - 1.f);
                split2(v, hi4[j], lo4[j]);
            }
            size_t o = (size_t)node * LDA + i4 * 4;
            *(ushort4*)(outhi + o) = *(ushort4*)hi4;
            if (outlo) *(ushort4*)(outlo + o) = *(ushort4*)lo4;
        } else if (i4 < 72) {
            ushort4 z = {0, 0, 0, 0};
            size_t o = (size_t)node * LDA + i4 * 4;
            *(ushort4*)(outhi + o) = z;
            if (outlo) *(ushort4*)(outlo + o) = z;
        }
    }
}

// ---------------- launch ----------------

extern "C" void kernel_launch(void* const* d_in, const int* in_sizes, int n_in,
                              void* d_out, int out_size, void* d_ws, size_t ws_size,
                              hipStream_t stream) {
    const float* x  = (const float*)d_in[0];
    const int*   ei = (const int*)d_in[1];
    const float* W[4]  = {(const float*)d_in[2],  (const float*)d_in[6],
                          (const float*)d_in[10], (const float*)d_in[14]};
    const float* As[4] = {(const float*)d_in[3],  (const float*)d_in[7],
                          (const float*)d_in[11], (const float*)d_in[15]};
    const float* Ad[4] = {(const float*)d_in[4],  (const float*)d_in[8],
                          (const float*)d_in[12], (const float*)d_in[16]};
    const float* Bb[4] = {(const float*)d_in[5],  (const float*)d_in[9],
                          (const float*)d_in[13], (const float*)d_in[17]};
    const float* Wh = (const float*)d_in[18];
    const float* bh = (const float*)d_in[19];

    // ---- workspace carve ----
    char* p = (char*)d_ws;
    ushort* hBb  = (ushort*)p;          p += (size_t)N_NODES * LDB * 2;      // xh bf16 payload
    ushort* hAhi = (ushort*)p;          p += (size_t)N_NODES * LDA * 2;      // A hi
    ushort* hAlo = (ushort*)p;          p += (size_t)N_NODES * LDA * 2;      // A lo (layer-3 only)
    float* as_  = (float*)p;            p += (size_t)N_NODES * HEADS * 4;
    float* ad_  = (float*)p;            p += (size_t)N_NODES * HEADS * 4;
    const int wsz0 = 4 * NT_HID * 512;   // layer-0: 4 k-panels
    const int wszH = 9 * NT_HID * 512;   // layers 1-3: 9 k-panels
    const int wszO = 9 * NT_HEAD * 512;  // head
    ushort* wfhi[4]; ushort* wflo[4];
    for (int l = 0; l < 4; ++l) {
        int sz = (l == 0) ? wsz0 : wszH;
        wfhi[l] = (ushort*)p; p += (size_t)sz * 2;
        wflo[l] = (ushort*)p; p += (size_t)sz * 2;
    }
    ushort* whhi = (ushort*)p; p += (size_t)wszO * 2;
    ushort* whlo = (ushort*)p; p += (size_t)wszO * 2;
    int* deg  = (int*)p;  p += N_NODES * 4;
    int* cur  = (int*)p;  p += N_NODES * 4;
    int* rowp = (int*)p;  p += (N_NODES + 1) * 4;
    int* csr  = (int*)p;  p += (size_t)TOT_E * 4;

    // ---- CSR build ----
    hipMemsetAsync(deg, 0, sizeof(int) * 2 * N_NODES, stream);  // deg + cur
    int egrid = (TOT_E + 255) / 256;
    deg_k<<<egrid, 256, 0, stream>>>(ei, deg);
    scan_k<<<1, 1024, 0, stream>>>(deg, rowp);
    fill_k<<<egrid, 256, 0, stream>>>(ei, rowp, cur, csr);

    // ---- weight + input conversion ----
    splitx_k<<<(N_NODES * IN_CH + 255) / 256, 256, 0, stream>>>(x, hAhi);
    {
        int tot = 4 * NT_HID * 64;
        convw_k<<<(tot + 255) / 256, 256, 0, stream>>>(W[0], As[0], Ad[0], IN_CH, DD,
                                                       NT_HID, wfhi[0], wflo[0], tot);
    }
    for (int l = 1; l < 4; ++l) {
        int tot = 9 * NT_HID * 64;
        convw_k<<<(tot + 255) / 256, 256, 0, stream>>>(W[l], As[l], Ad[l], DD, DD,
                                                       NT_HID, wfhi[l], wflo[l], tot);
    }
    {
        int tot = 9 * NT_HEAD * 64;
        convw_k<<<(tot + 255) / 256, 256, 0, stream>>>(Wh, nullptr, nullptr, DD, OUTW,
                                                       NT_HEAD, whhi, whlo, tot);
    }

    dim3 gG((N_NODES + 127) / 128, 2);   // hidden: 18 tiles = 9 + 9 (incl. stats tile)
    dim3 gO((N_NODES + 127) / 128, 1);   // head: 9 tiles
    int ggrid = N_NODES / 4;             // 5000, exact

    for (int l = 0; l < 4; ++l) {
        int kp = (l == 0) ? 4 : 9;
        gemm2_k<<<gG, 256, 0, stream>>>(hAhi, nullptr, LDA, kp,
                                        wfhi[l], wflo[l], NT_HID,
                                        hBb, as_, ad_, nullptr, 0, 0, nullptr);
        gat_k<<<ggrid, 256, 0, stream>>>(hBb, as_, ad_, rowp, csr, Bb[l],
                                         hAhi, (l == 3) ? hAlo : nullptr);
    }

    // head readout (3-term for output precision) -> fp32 out [N, 132]
    gemm2_k<<<gO, 256, 0, stream>>>(hAhi, hAlo, LDA, 9,
                                    whhi, whlo, NT_HEAD,
                                    nullptr, nullptr, nullptr,
                                    (float*)d_out, OUTW, OUTW, bh);
}

// Round 8
// 554.393 us; speedup vs baseline: 1.1434x; 1.1434x over previous
//
#include <hip/hip_runtime.h>
#include <hip/hip_bf16.h>

#define N_NODES 20000
#define N_EDGES 320000
#define TOT_E   (N_EDGES + N_NODES)   // 340000 with self loops
#define IN_CH   128
#define HEADS   8
#define CH      33
#define DD      264                   // HEADS*CH
#define OUTW    132
#define NEG     0.2f

#define LDB     272                   // bf16 payload row stride
#define LDA     288                   // hA bf16 row stride, K padded to 9*32
#define NT_HID  18                    // 17 payload tiles + 1 stats tile [was|wad]
#define NT_HEAD 12                    // head gemm tiles (132 -> 192, zero-padded)
#define NTG     6                     // compile-time tiles per y-group

typedef unsigned short ushort;
typedef short bf16x8 __attribute__((ext_vector_type(8)));
typedef float f32x4  __attribute__((ext_vector_type(4)));

__device__ inline void split2(float v, ushort& hi, ushort& lo) {
    __hip_bfloat16 h = __float2bfloat16(v);
    float r = v - __bfloat162float(h);
    __hip_bfloat16 l = __float2bfloat16(r);
    hi = *(ushort*)&h;
    lo = *(ushort*)&l;
}

__device__ inline float bf2f(ushort u) {
    union { unsigned int i; float f; } c;
    c.i = ((unsigned int)u) << 16;
    return c.f;
}

// ---------------- CSR build ----------------

__global__ void deg_k(const int* __restrict__ ei, int* __restrict__ deg) {
    int e = blockIdx.x * 256 + threadIdx.x;
    if (e >= TOT_E) return;
    int dst = (e < N_EDGES) ? ei[N_EDGES + e] : (e - N_EDGES);
    atomicAdd(&deg[dst], 1);
}

__global__ __launch_bounds__(1024) void scan_k(const int* __restrict__ deg,
                                               int* __restrict__ rowp) {
    __shared__ int part[1024];
    const int PER = 20;
    int t = threadIdx.x;
    int base = t * PER;
    int s = 0;
    for (int i = 0; i < PER; ++i) {
        int idx = base + i;
        if (idx < N_NODES) s += deg[idx];
    }
    part[t] = s;
    __syncthreads();
    for (int off = 1; off < 1024; off <<= 1) {
        int v = 0;
        if (t >= off) v = part[t - off];
        __syncthreads();
        part[t] += v;
        __syncthreads();
    }
    int run = part[t] - s;
    for (int i = 0; i < PER; ++i) {
        int idx = base + i;
        if (idx < N_NODES) { rowp[idx] = run; run += deg[idx]; }
    }
    if (t == 1023) rowp[N_NODES] = part[1023];
}

__global__ void fill_k(const int* __restrict__ ei, const int* __restrict__ rowp,
                       int* __restrict__ cur, int* __restrict__ csr) {
    int e = blockIdx.x * 256 + threadIdx.x;
    if (e >= TOT_E) return;
    int src, dst;
    if (e < N_EDGES) { src = ei[e]; dst = ei[N_EDGES + e]; }
    else             { src = dst = e - N_EDGES; }
    int p = atomicAdd(&cur[dst], 1);
    csr[rowp[dst] + p] = src;
}

// ---------------- input x -> bf16 (into hAhi, stride LDA) ----------------

__global__ void splitx_k(const float* __restrict__ x, ushort* __restrict__ ahi) {
    int idx = blockIdx.x * 256 + threadIdx.x;
    if (idx >= N_NODES * IN_CH) return;
    int n = idx >> 7, k = idx & 127;
    __hip_bfloat16 h = __float2bfloat16(x[idx]);
    ahi[(size_t)n * LDA + k] = *(ushort*)&h;
}

// ---------------- weight -> fragment-ordered hi/lo bf16 (+ optional stats tile) ------
// Wfrag[((p*NT + t)*64 + kq*16 + m)*8 + j] = V[p*32 + kq*8 + j][t*16 + m]
// last tile (when a_s given): col m<8 -> W·a_s per head m; m>=8 -> W·a_d per head m-8.

__global__ void convw_k(const float* __restrict__ W, const float* __restrict__ a_s,
                        const float* __restrict__ a_d, int K, int NC, int NT,
                        ushort* __restrict__ fhi, ushort* __restrict__ flo,
                        int total) {
    int gid = blockIdx.x * 256 + threadIdx.x;
    if (gid >= total) return;   // total = panels*NT*64
    int p = gid / (NT * 64);
    int rem = gid % (NT * 64);
    int t = rem >> 6, c = rem & 63;
    int kq = c >> 4, m = c & 15;
    int n = t * 16 + m;
    bool stats = (a_s != nullptr) && (t == NT - 1);
    ushort hi8[8], lo8[8];
#pragma unroll
    for (int j = 0; j < 8; ++j) {
        int k = p * 32 + kq * 8 + j;
        float v = 0.f;
        if (k < K) {
            if (stats) {
                const float* av = (m < 8) ? a_s : a_d;
                int h = (m < 8) ? m : m - 8;
                const float* wr = W + (size_t)k * NC + h * CH;
                float s = 0.f;
                for (int cc = 0; cc < CH; ++cc) s += wr[cc] * av[h * CH + cc];
                v = s;
            } else if (n < NC) {
                v = W[(size_t)k * NC + n];
            }
        }
        split2(v, hi8[j], lo8[j]);
    }
    size_t o = ((size_t)gid) * 8;
#pragma unroll
    for (int j = 0; j < 8; ++j) { fhi[o + j] = hi8[j]; flo[o + j] = lo8[j]; }
}

// ---------------- MFMA GEMM, M-tile 128, B via LDS, compile-time 6-tile group --------
// Wave w owns m-tiles 2w, 2w+1. Hidden (C==null): bf16 payload tiles<17, stats tile 17.
// Head: fp32 C + bias, 3-term (Alo).

__global__ __launch_bounds__(256) void gemm2_k(
    const ushort* __restrict__ Ahi, const ushort* __restrict__ Alo, int lda, int kpanels,
    const ushort* __restrict__ Bhi, const ushort* __restrict__ Blo, int NTtot,
    ushort* __restrict__ Cb16, float* __restrict__ as_, float* __restrict__ ad_,
    float* __restrict__ C, int ldc, int ncguard, const float* __restrict__ bias) {
    __shared__ ushort Albuf[2][8][512];    // [hi/lo][m-subtile][chunk*8] = 16 KB
    __shared__ ushort Blbuf[2][NTG][512];  // 12 KB
    int tid = threadIdx.x;
    int m0 = blockIdx.x * 128;
    int t0 = blockIdx.y * NTG;
    bool use3 = (Alo != nullptr);

    f32x4 acc[2][NTG];
#pragma unroll
    for (int mt = 0; mt < 2; ++mt)
#pragma unroll
        for (int t = 0; t < NTG; ++t) acc[mt][t] = (f32x4){0.f, 0.f, 0.f, 0.f};

    int w = tid >> 6, lane = tid & 63;

    for (int p = 0; p < kpanels; ++p) {
        // stage A (coalesced 64-B rows)
        int nA = use3 ? 1024 : 512;
        for (int id = tid; id < nA; id += 256) {
            int hl = id >> 9;
            int cid = id & 511;
            int mrow = cid >> 2, kq = cid & 3;
            int gm = m0 + mrow;
            uint4 v = {0, 0, 0, 0};
            if (gm < N_NODES) {
                const ushort* src = (hl ? Alo : Ahi) + (size_t)gm * lda + p * 32 + kq * 8;
                v = *(const uint4*)src;
            }
            *(uint4*)&Albuf[hl][mrow >> 4][(kq * 16 + (mrow & 15)) * 8] = v;
        }
        // stage B: 2*NTG*64 = 768 contiguous 16-B chunks (conflict-free)
        for (int id = tid; id < 2 * NTG * 64; id += 256) {
            int hl = id / (NTG * 64);
            int rem = id % (NTG * 64);
            int t = rem >> 6, c = rem & 63;
            const ushort* src = (hl ? Blo : Bhi) + ((size_t)(p * NTtot + t0 + t) * 64 + c) * 8;
            *(uint4*)&Blbuf[hl][t][c * 8] = *(const uint4*)src;
        }
        __syncthreads();

        bf16x8 a0 = *(const bf16x8*)&Albuf[0][2 * w][lane * 8];
        bf16x8 a1 = *(const bf16x8*)&Albuf[0][2 * w + 1][lane * 8];
        bf16x8 l0, l1;
        if (use3) {
            l0 = *(const bf16x8*)&Albuf[1][2 * w][lane * 8];
            l1 = *(const bf16x8*)&Albuf[1][2 * w + 1][lane * 8];
        }
#pragma unroll
        for (int t = 0; t < NTG; ++t) {
            bf16x8 bh = *(const bf16x8*)&Blbuf[0][t][lane * 8];
            bf16x8 bl = *(const bf16x8*)&Blbuf[1][t][lane * 8];
            acc[0][t] = __builtin_amdgcn_mfma_f32_16x16x32_bf16(a0, bh, acc[0][t], 0, 0, 0);
            acc[1][t] = __builtin_amdgcn_mfma_f32_16x16x32_bf16(a1, bh, acc[1][t], 0, 0, 0);
            acc[0][t] = __builtin_amdgcn_mfma_f32_16x16x32_bf16(a0, bl, acc[0][t], 0, 0, 0);
            acc[1][t] = __builtin_amdgcn_mfma_f32_16x16x32_bf16(a1, bl, acc[1][t], 0, 0, 0);
            if (use3) {
                acc[0][t] = __builtin_amdgcn_mfma_f32_16x16x32_bf16(l0, bh, acc[0][t], 0, 0, 0);
                acc[1][t] = __builtin_amdgcn_mfma_f32_16x16x32_bf16(l1, bh, acc[1][t], 0, 0, 0);
            }
        }
        __syncthreads();
    }

    // store: C/D layout col = lane&15, row = (lane>>4)*4 + r
    int col = lane & 15;
#pragma unroll
    for (int mt = 0; mt < 2; ++mt) {
        int rbase = m0 + (2 * w + mt) * 16 + ((lane >> 4) << 2);
#pragma unroll
        for (int t = 0; t < NTG; ++t) {
            int tg = t0 + t;
#pragma unroll
            for (int r = 0; r < 4; ++r) {
                int gm = rbase + r;
                if (gm >= N_NODES) continue;
                float v = acc[mt][t][r];
                if (C) {
                    int gn = tg * 16 + col;
                    if (gn < ncguard) C[(size_t)gm * ldc + gn] = v + bias[gn];
                } else if (tg < 17) {
                    __hip_bfloat16 bv = __float2bfloat16(v);
                    Cb16[(size_t)gm * LDB + tg * 16 + col] = *(ushort*)&bv;
                } else {
                    if (col < 8) as_[(size_t)gm * 8 + col] = v;
                    else         ad_[(size_t)gm * 8 + col - 8] = v;
                }
            }
        }
    }
}

// ---------------- fused softmax + gather-aggregate (unchanged) ----------------

__global__ __launch_bounds__(256) void gat_k(
    const ushort* __restrict__ xb, const float* __restrict__ as_,
    const float* __restrict__ ad_, const int* __restrict__ rowp,
    const int* __restrict__ csr, const float* __restrict__ bias,
    ushort* __restrict__ outhi, ushort* __restrict__ outlo) {
    int wv = threadIdx.x >> 6, lane = threadIdx.x & 63;
    int node = blockIdx.x * 4 + wv;   // grid is exactly N/4
    int r0 = rowp[node], dg = rowp[node + 1] - r0;

    __shared__ float lex[4][64][8];
    __shared__ int   lsrc[4][64];
    __shared__ int   bdg[4];

    if (lane == 0) bdg[wv] = dg;
    __syncthreads();
    int bmax = max(max(bdg[0], bdg[1]), max(bdg[2], bdg[3]));
    int nchunks = (bmax + 63) >> 6;

    float ad[8];
#pragma unroll
    for (int h = 0; h < 8; ++h) ad[h] = ad_[node * 8 + h];

    float mx[8], iv[8], e8[8];
    int myS = node;
    bool fast = (dg <= 64);
    if (fast) {
#pragma unroll
        for (int h = 0; h < 8; ++h) e8[h] = -1e30f;
        if (lane < dg) {
            myS = csr[r0 + lane];
            const float* ap = as_ + (size_t)myS * 8;
#pragma unroll
            for (int h = 0; h < 8; ++h) {
                float e = ap[h] + ad[h];
                e8[h] = e > 0.f ? e : NEG * e;
            }
        }
#pragma unroll
        for (int h = 0; h < 8; ++h) {
            float m = e8[h];
            for (int off = 32; off; off >>= 1) m = fmaxf(m, __shfl_xor(m, off, 64));
            mx[h] = m;
        }
#pragma unroll
        for (int h = 0; h < 8; ++h) {
            float ex = (lane < dg) ? __expf(e8[h] - mx[h]) : 0.f;
            e8[h] = ex;
            float s = ex;
            for (int off = 32; off; off >>= 1) s += __shfl_xor(s, off, 64);
            iv[h] = 1.0f / (s + 1e-16f);
        }
    } else {
#pragma unroll
        for (int h = 0; h < 8; ++h) mx[h] = -1e30f;
        for (int j = lane; j < dg; j += 64) {
            int s = csr[r0 + j];
            const float* ap = as_ + (size_t)s * 8;
#pragma unroll
            for (int h = 0; h < 8; ++h) {
                float e = ap[h] + ad[h];
                e = e > 0.f ? e : NEG * e;
                mx[h] = fmaxf(mx[h], e);
            }
        }
#pragma unroll
        for (int h = 0; h < 8; ++h)
            for (int off = 32; off; off >>= 1)
                mx[h] = fmaxf(mx[h], __shfl_xor(mx[h], off, 64));
        float sm[8] = {0.f, 0.f, 0.f, 0.f, 0.f, 0.f, 0.f, 0.f};
        for (int j = lane; j < dg; j += 64) {
            int s = csr[r0 + j];
            const float* ap = as_ + (size_t)s * 8;
#pragma unroll
            for (int h = 0; h < 8; ++h) {
                float e = ap[h] + ad[h];
                e = e > 0.f ? e : NEG * e;
                sm[h] += __expf(e - mx[h]);
            }
        }
#pragma unroll
        for (int h = 0; h < 8; ++h) {
            for (int off = 32; off; off >>= 1) sm[h] += __shfl_xor(sm[h], off, 64);
            iv[h] = 1.0f / (sm[h] + 1e-16f);
        }
    }

    int h0[4], h1[4];
#pragma unroll
    for (int j = 0; j < 4; ++j) {
        h0[j] = (4 * lane + j) / 33;
        h1[j] = (4 * (lane + 64) + j) / 33;   // lanes 0,1 only (always head 7)
    }
    float4 a0 = {0.f, 0.f, 0.f, 0.f}, a1 = {0.f, 0.f, 0.f, 0.f};

    for (int c = 0; c < nchunks; ++c) {
        int base = c << 6, j = base + lane;
        __syncthreads();
        int s = node;
        float al[8];
#pragma unroll
        for (int h = 0; h < 8; ++h) al[h] = 0.f;
        if (j < dg) {
            if (fast) {
                s = myS;
#pragma unroll
                for (int h = 0; h < 8; ++h) al[h] = e8[h] * iv[h];
            } else {
                s = csr[r0 + j];
                const float* ap = as_ + (size_t)s * 8;
#pragma unroll
                for (int h = 0; h < 8; ++h) {
                    float e = ap[h] + ad[h];
                    e = e > 0.f ? e : NEG * e;
                    al[h] = __expf(e - mx[h]) * iv[h];
                }
            }
        }
        lsrc[wv][lane] = s;
#pragma unroll
        for (int h = 0; h < 8; ++h) lex[wv][lane][h] = al[h];
        __syncthreads();

        int rem = dg - base;
        int cnt = rem > 64 ? 64 : (rem < 0 ? 0 : rem);
        int cnt4 = (cnt + 3) & ~3;
        for (int jj = 0; jj < cnt4; jj += 4) {
            int s0 = lsrc[wv][jj + 0], s1 = lsrc[wv][jj + 1];
            int s2 = lsrc[wv][jj + 2], s3 = lsrc[wv][jj + 3];
            const ushort4* p0 = (const ushort4*)(xb + (size_t)s0 * LDB);
            const ushort4* p1 = (const ushort4*)(xb + (size_t)s1 * LDB);
            const ushort4* p2 = (const ushort4*)(xb + (size_t)s2 * LDB);
            const ushort4* p3 = (const ushort4*)(xb + (size_t)s3 * LDB);
            ushort4 v0 = p0[lane], v1 = p1[lane], v2 = p2[lane], v3 = p3[lane];
            ushort4 w0, w1, w2, w3;
            if (lane < 2) { w0 = p0[64 + lane]; w1 = p1[64 + lane]; w2 = p2[64 + lane]; w3 = p3[64 + lane]; }
            const float* x0 = lex[wv][jj + 0];
            const float* x1 = lex[wv][jj + 1];
            const float* x2 = lex[wv][jj + 2];
            const float* x3 = lex[wv][jj + 3];
            a0.x += x0[h0[0]] * bf2f(v0.x) + x1[h0[0]] * bf2f(v1.x)
                  + x2[h0[0]] * bf2f(v2.x) + x3[h0[0]] * bf2f(v3.x);
            a0.y += x0[h0[1]] * bf2f(v0.y) + x1[h0[1]] * bf2f(v1.y)
                  + x2[h0[1]] * bf2f(v2.y) + x3[h0[1]] * bf2f(v3.y);
            a0.z += x0[h0[2]] * bf2f(v0.z) + x1[h0[2]] * bf2f(v1.z)
                  + x2[h0[2]] * bf2f(v2.z) + x3[h0[2]] * bf2f(v3.z);
            a0.w += x0[h0[3]] * bf2f(v0.w) + x1[h0[3]] * bf2f(v1.w)
                  + x2[h0[3]] * bf2f(v2.w) + x3[h0[3]] * bf2f(v3.w);
            if (lane < 2) {
                a1.x += x0[h1[0]] * bf2f(w0.x) + x1[h1[0]] * bf2f(w1.x)
                      + x2[h1[0]] * bf2f(w2.x) + x3[h1[0]] * bf2f(w3.x);
                a1.y += x0[h1[1]] * bf2f(w0.y) + x1[h1[1]] * bf2f(w1.y)
                      + x2[h1[1]] * bf2f(w2.y) + x3[h1[1]] * bf2f(w3.y);
                a1.z += x0[h1[2]] * bf2f(w0.z) + x1[h1[2]] * bf2f(w1.z)
                      + x2[h1[2]] * bf2f(w2.z) + x3[h1[2]] * bf2f(w3.z);
                a1.w += x0[h1[3]] * bf2f(w0.w) + x1[h1[3]] * bf2f(w1.w)
                      + x2[h1[3]] * bf2f(w2.w) + x3[h1[3]] * bf2f(w3.w);
            }
        }
    }

    // epilogue: bias + elu, bf16 (hi) out; lo only when requested (head-gemm input)
#pragma unroll
    for (int k = 0; k < 2; ++k) {
        int i4 = lane + 64 * k;
        if (i4 < 66) {
            float4 a = (k == 0) ? a0 : a1;
            float vals[4] = {a.x, a.y, a.z, a.w};
            ushort hi4[4], lo4[4];
#pragma unroll
            for (int j = 0; j < 4; ++j) {
                float v = vals[j] + bias[i4 * 4 + j];
                v = v > 0.f ? v : (__expf(v) - 1.f);
                split2(v, hi4[j], lo4[j]);
            }
            size_t o = (size_t)node * LDA + i4 * 4;
            *(ushort4*)(outhi + o) = *(ushort4*)hi4;
            if (outlo) *(ushort4*)(outlo + o) = *(ushort4*)lo4;
        } else if (i4 < 72) {
            ushort4 z = {0, 0, 0, 0};
            size_t o = (size_t)node * LDA + i4 * 4;
            *(ushort4*)(outhi + o) = z;
            if (outlo) *(ushort4*)(outlo + o) = z;
        }
    }
}

// ---------------- launch ----------------

extern "C" void kernel_launch(void* const* d_in, const int* in_sizes, int n_in,
                              void* d_out, int out_size, void* d_ws, size_t ws_size,
                              hipStream_t stream) {
    const float* x  = (const float*)d_in[0];
    const int*   ei = (const int*)d_in[1];
    const float* W[4]  = {(const float*)d_in[2],  (const float*)d_in[6],
                          (const float*)d_in[10], (const float*)d_in[14]};
    const float* As[4] = {(const float*)d_in[3],  (const float*)d_in[7],
                          (const float*)d_in[11], (const float*)d_in[15]};
    const float* Ad[4] = {(const float*)d_in[4],  (const float*)d_in[8],
                          (const float*)d_in[12], (const float*)d_in[16]};
    const float* Bb[4] = {(const float*)d_in[5],  (const float*)d_in[9],
                          (const float*)d_in[13], (const float*)d_in[17]};
    const float* Wh = (const float*)d_in[18];
    const float* bh = (const float*)d_in[19];

    // ---- workspace carve ----
    char* p = (char*)d_ws;
    ushort* hBb  = (ushort*)p;          p += (size_t)N_NODES * LDB * 2;      // xh bf16 payload
    ushort* hAhi = (ushort*)p;          p += (size_t)N_NODES * LDA * 2;      // A hi
    ushort* hAlo = (ushort*)p;          p += (size_t)N_NODES * LDA * 2;      // A lo (layer-3 only)
    float* as_  = (float*)p;            p += (size_t)N_NODES * HEADS * 4;
    float* ad_  = (float*)p;            p += (size_t)N_NODES * HEADS * 4;
    const int wsz0 = 4 * NT_HID * 512;   // layer-0: 4 k-panels
    const int wszH = 9 * NT_HID * 512;   // layers 1-3: 9 k-panels
    const int wszO = 9 * NT_HEAD * 512;  // head (12 tiles incl. zero pad)
    ushort* wfhi[4]; ushort* wflo[4];
    for (int l = 0; l < 4; ++l) {
        int sz = (l == 0) ? wsz0 : wszH;
        wfhi[l] = (ushort*)p; p += (size_t)sz * 2;
        wflo[l] = (ushort*)p; p += (size_t)sz * 2;
    }
    ushort* whhi = (ushort*)p; p += (size_t)wszO * 2;
    ushort* whlo = (ushort*)p; p += (size_t)wszO * 2;
    int* deg  = (int*)p;  p += N_NODES * 4;
    int* cur  = (int*)p;  p += N_NODES * 4;
    int* rowp = (int*)p;  p += (N_NODES + 1) * 4;
    int* csr  = (int*)p;  p += (size_t)TOT_E * 4;

    // ---- CSR build ----
    hipMemsetAsync(deg, 0, sizeof(int) * 2 * N_NODES, stream);  // deg + cur
    int egrid = (TOT_E + 255) / 256;
    deg_k<<<egrid, 256, 0, stream>>>(ei, deg);
    scan_k<<<1, 1024, 0, stream>>>(deg, rowp);
    fill_k<<<egrid, 256, 0, stream>>>(ei, rowp, cur, csr);

    // ---- weight + input conversion ----
    splitx_k<<<(N_NODES * IN_CH + 255) / 256, 256, 0, stream>>>(x, hAhi);
    {
        int tot = 4 * NT_HID * 64;
        convw_k<<<(tot + 255) / 256, 256, 0, stream>>>(W[0], As[0], Ad[0], IN_CH, DD,
                                                       NT_HID, wfhi[0], wflo[0], tot);
    }
    for (int l = 1; l < 4; ++l) {
        int tot = 9 * NT_HID * 64;
        convw_k<<<(tot + 255) / 256, 256, 0, stream>>>(W[l], As[l], Ad[l], DD, DD,
                                                       NT_HID, wfhi[l], wflo[l], tot);
    }
    {
        int tot = 9 * NT_HEAD * 64;
        convw_k<<<(tot + 255) / 256, 256, 0, stream>>>(Wh, nullptr, nullptr, DD, OUTW,
                                                       NT_HEAD, whhi, whlo, tot);
    }

    dim3 gG((N_NODES + 127) / 128, NT_HID / NTG);   // 157 x 3
    dim3 gO((N_NODES + 127) / 128, NT_HEAD / NTG);  // 157 x 2
    int ggrid = N_NODES / 4;                        // 5000, exact

    for (int l = 0; l < 4; ++l) {
        int kp = (l == 0) ? 4 : 9;
        gemm2_k<<<gG, 256, 0, stream>>>(hAhi, nullptr, LDA, kp,
                                        wfhi[l], wflo[l], NT_HID,
                                        hBb, as_, ad_, nullptr, 0, 0, nullptr);
        gat_k<<<ggrid, 256, 0, stream>>>(hBb, as_, ad_, rowp, csr, Bb[l],
                                         hAhi, (l == 3) ? hAlo : nullptr);
    }

    // head readout (3-term for output precision) -> fp32 out [N, 132]
    gemm2_k<<<gO, 256, 0, stream>>>(hAhi, hAlo, LDA, 9,
                                    whhi, whlo, NT_HEAD,
                                    nullptr, nullptr, nullptr,
                                    (float*)d_out, OUTW, OUTW, bh);
}